// Round 20
// baseline (278.288 us; speedup 1.0000x reference)
//
#include <hip/hip_runtime.h>
#include <hip/hip_bf16.h>
#include <stdint.h>

typedef __attribute__((ext_vector_type(8))) short short8;
typedef __attribute__((ext_vector_type(4))) float f32x4;

#define M_ROWS 8192
#define K_DIM  4096
#define N_COLS 4096
#define NT     (K_DIM / 64)   // 64 K-tiles
#define WL_CAP (1 << 20)

// sqrt(2) in fp64: 0x3FF6A09E667F3BCD (slightly ABOVE true sqrt2).
#define SQRT2_MANT 0x6A09E667F3BCDLL
// fp32 equivalent: m23 >= 0x3504F4  <=>  (m23<<29) >= SQRT2_MANT  (exact; HW-validated in quant)
#define SQRT2_M23 0x3504F4
// flag margin: ~2^-11 relative in m23 units (ceil(3.11e12/2^29)=5794; 5800 = safe superset)
#define FLAG_M23 5800

__device__ __forceinline__ int rlog2_mask(double a) {
    if (!(a > 1e-38)) return -128;
    long long b = __double_as_longlong(a);
    int E = (int)(b >> 52) - 1023;
    long long m = b & 0xFFFFFFFFFFFFFLL;
    int e = E + (int)(m >= SQRT2_MANT);
    return e < -128 ? -128 : (e > 127 ? 127 : e);
}

__device__ __forceinline__ double pow2d(int e) {
    return __longlong_as_double((long long)(e + 1023) << 52);
}

__device__ __forceinline__ unsigned short bf16_pow2(int e) {
    if (e >= -126) return (unsigned short)((e + 127) << 7);
    int sh = 133 + e;
    return (unsigned short)(sh >= 0 ? (1 << sh) : 0);
}

__device__ __forceinline__ int bf16_exp(unsigned short u) {
    int ex = (u >> 7) & 0xFF;
    if (ex) return ex - 127;
    int m = u & 0x7F;
    return m ? (-133 + (31 - __clz(m))) : -1000;
}

__device__ __forceinline__ float finalize_out(int em, int ebj) {
    double s = pow2d(em) + pow2d(ebj);
    return (float)pow2d(rlog2_mask(s));
}

// ---------------- fused prep: wl_count reset + bias quant + x/w quant ----------------
__device__ __forceinline__ unsigned short qbf16(float f) {
    unsigned u = __float_as_uint(f) & 0x7FFFFFFFu;  // |f| bits
    int E = (int)(u >> 23);
    if (E == 0 || E == 255) {
        return bf16_pow2(rlog2_mask(fabs((double)f)));  // denorm/zero/inf/nan slow path
    }
    int e = (E - 127) + (int)((u & 0x7FFFFFu) >= SQRT2_M23);
    e = e > 127 ? 127 : e;
    return (unsigned short)((e + 127) << 7);
}

__device__ __forceinline__ ushort4 quant4(float4 v) {
    ushort4 o;
    o.x = qbf16(v.x);
    o.y = qbf16(v.y);
    o.z = qbf16(v.z);
    o.w = qbf16(v.w);
    return o;
}

__global__ void prep_kernel(const float* __restrict__ x, const float* __restrict__ w,
                            const float* __restrict__ bias,
                            unsigned short* __restrict__ xq, unsigned short* __restrict__ wq,
                            int* __restrict__ eb, int* __restrict__ wl_count,
                            int nx4, int nw4) {
    int idx = blockIdx.x * blockDim.x + threadIdx.x;
    if (idx == 0) *wl_count = 0;
    if (idx < N_COLS) eb[idx] = rlog2_mask(fabs((double)bias[idx]));
    int stride = gridDim.x * blockDim.x;
    int total = nx4 + nw4;
    for (int i = idx; i < total; i += stride) {
        if (i < nx4) {
            float4 v = ((const float4*)x)[i];
            ((ushort4*)xq)[i] = quant4(v);
        } else {
            float4 v = ((const float4*)w)[i - nx4];
            ((ushort4*)wq)[i - nx4] = quant4(v);
        }
    }
}

// ---------------- 256x256 GEMM (R17 schedule; all-integer epilogue) ----------------
__device__ __forceinline__ void g2lds16(const unsigned short* g, unsigned short* l) {
    __builtin_amdgcn_global_load_lds(
        (const __attribute__((address_space(1))) unsigned int*)g,
        (__attribute__((address_space(3))) unsigned int*)l, 16, 0, 0);
}

#define LD8(p, off) (*(const short8*)((const char*)(p) + (off)))
#define MFMA16(a, b, c) __builtin_amdgcn_mfma_f32_16x16x32_bf16((a), (b), (c), 0, 0, 0)

__global__ __launch_bounds__(512, 2) void gemm_kernel(
    const unsigned short* __restrict__ xq, const unsigned short* __restrict__ wq,
    const int* __restrict__ eb, float* __restrict__ out,
    int* __restrict__ wl_count, int* __restrict__ wl)
{
    // Per 64KB buffer (shorts): A0 [0,8192) A1 [8192,16384) B0 [16384,24576) B1 [24576,32768)
    // 16KB half-tile = [2 kk][128 rows][32 cols] bf16, 64B row pitch,
    // st_16x32 swizzle: byte ^= ((byte>>9)&1)<<5.
    __shared__ unsigned short lds[2][32768];

    const int tid = threadIdx.x;
    const int lane = tid & 63, w = tid >> 6;
    const int wm = w >> 2, wn = w & 3;
    const int l15 = lane & 15, lhi = lane >> 4;

    // Persistent 2D XCD tiling: 256 blocks (1/CU), each does 2 M-tiles.
    const int x = blockIdx.x & 7;
    const int j = blockIdx.x >> 3;          // 0..31
    const int bm0 = (x & 3) * 8 + (j & 3);  // tile 1; tile 2 = bm0 + 4
    const int bn  = (x >> 2) * 8 + (j >> 2);
    const int bcol = bn * 256;

    // staging thread->coord (pre-swizzled global, linear LDS dest)
    int p0 = tid * 16;
    int lin0 = p0 ^ (((p0 >> 9) & 1) << 5);
    int row0 = (lin0 >> 6) & 127;
    int col0 = (((lin0 >> 13) << 6) | (lin0 & 63)) >> 1;
    int p1 = 8192 + tid * 16;
    int lin1 = p1 ^ (((p1 >> 9) & 1) << 5);
    int row1 = (lin1 >> 6) & 127;
    int col1 = (((lin1 >> 13) << 6) | (lin1 & 63)) >> 1;

    // fragment read base (bytes, swizzled)
    int fsw = l15 * 64 + lhi * 16;
    fsw ^= ((l15 >> 3) & 1) << 5;

    const char* pA_0 = (const char*)&lds[0][wm * 8192] + fsw;
    const char* pA_1 = (const char*)&lds[1][wm * 8192] + fsw;
    const char* pB_0 = (const char*)&lds[0][16384 + (wn >> 1) * 8192 + (wn & 1) * 2048] + fsw;
    const char* pB_1 = (const char*)&lds[1][16384 + (wn >> 1) * 8192 + (wn & 1) * 2048] + fsw;

#define STAGE_A(b, h, OFFE) do { \
        g2lds16(((h) ? aS0h1 : aS0h0) + (OFFE), &lds[b][(h) * 8192] + wofs); \
        g2lds16(((h) ? aS1h1 : aS1h0) + (OFFE), &lds[b][(h) * 8192 + 4096] + wofs); \
    } while (0)
#define STAGE_B(b, h, OFFE) do { \
        g2lds16(((h) ? bS0h1 : bS0h0) + (OFFE), &lds[b][16384 + (h) * 8192] + wofs); \
        g2lds16(((h) ? bS1h1 : bS1h0) + (OFFE), &lds[b][16384 + (h) * 8192 + 4096] + wofs); \
    } while (0)
#define DS_A4(P, mb) do { \
        aF[0][0] = LD8(P, ((mb) + 0) * 1024); aF[0][1] = LD8(P, ((mb) + 0) * 1024 + 8192); \
        aF[1][0] = LD8(P, ((mb) + 1) * 1024); aF[1][1] = LD8(P, ((mb) + 1) * 1024 + 8192); \
        aF[2][0] = LD8(P, ((mb) + 2) * 1024); aF[2][1] = LD8(P, ((mb) + 2) * 1024 + 8192); \
        aF[3][0] = LD8(P, ((mb) + 3) * 1024); aF[3][1] = LD8(P, ((mb) + 3) * 1024 + 8192); \
    } while (0)
#define DS_B2(P, arr, cb) do { \
        arr[0][0] = LD8(P, ((cb) + 0) * 1024); arr[0][1] = LD8(P, ((cb) + 0) * 1024 + 8192); \
        arr[1][0] = LD8(P, ((cb) + 1) * 1024); arr[1][1] = LD8(P, ((cb) + 1) * 1024 + 8192); \
    } while (0)
#define MFMA_Q(mb, nb, B) do { \
        _Pragma("unroll") \
        for (int m_ = 0; m_ < 4; ++m_) \
        _Pragma("unroll") \
        for (int n_ = 0; n_ < 2; ++n_) { \
            acc[(mb) + m_][(nb) + n_] = MFMA16(aF[m_][0], B[n_][0], acc[(mb) + m_][(nb) + n_]); \
            acc[(mb) + m_][(nb) + n_] = MFMA16(aF[m_][1], B[n_][1], acc[(mb) + m_][(nb) + n_]); \
        } \
    } while (0)

#define BAR()  __builtin_amdgcn_s_barrier()
#define PRIO1() __builtin_amdgcn_s_setprio(1)
#define PRIO0() __builtin_amdgcn_s_setprio(0)

    const int wofs = w * 512;

    for (int ht = 0; ht < 2; ++ht) {
        const int bm = bm0 + ht * 4;
        const int brow = bm * 256;

        // 8 rolling global pointers (advance +128 elems / iteration = 2 K-tiles)
        const unsigned short* aS0h0 = xq + (size_t)(brow + row0) * K_DIM + col0;
        const unsigned short* aS1h0 = xq + (size_t)(brow + row1) * K_DIM + col1;
        const unsigned short* aS0h1 = aS0h0 + (size_t)128 * K_DIM;
        const unsigned short* aS1h1 = aS1h0 + (size_t)128 * K_DIM;
        const unsigned short* bS0h0 = wq + (size_t)(bcol + row0) * K_DIM + col0;
        const unsigned short* bS1h0 = wq + (size_t)(bcol + row1) * K_DIM + col1;
        const unsigned short* bS0h1 = bS0h0 + (size_t)128 * K_DIM;
        const unsigned short* bS1h1 = bS1h0 + (size_t)128 * K_DIM;

        f32x4 acc[8][4];
#pragma unroll
        for (int m = 0; m < 8; ++m)
#pragma unroll
            for (int n = 0; n < 4; ++n) acc[m][n] = (f32x4){0.f, 0.f, 0.f, 0.f};

        short8 aF[4][2], b01[2][2], b23[2][2];

        // ---- prologue: tile0 -> buf0 (A0,A1,B0,B1), tile1 -> buf1 (B0,B1) ----
        STAGE_A(0, 0, 0);
        STAGE_A(0, 1, 0);
        STAGE_B(0, 0, 0);
        STAGE_B(0, 1, 0);
        STAGE_B(1, 0, 64);
        STAGE_B(1, 1, 64);
        asm volatile("s_waitcnt vmcnt(4)" ::: "memory");
        BAR();

        // ---- main loop: 2 K-tiles (2tt -> buf0, 2tt+1 -> buf1), 4 mega-phases ----
        for (int tt = 0; tt < NT / 2 - 1; ++tt) {
            // P1: tile t (buf0) m0-3 x all n; stage buf1.A (t+1)
            DS_B2(pB_0, b01, 0); DS_B2(pB_0, b23, 2);
            DS_A4(pA_0, 0);
            STAGE_A(1, 0, 64); STAGE_A(1, 1, 64);
            PRIO1(); MFMA_Q(0, 0, b01); MFMA_Q(0, 2, b23); PRIO0(); BAR();
            // P2: tile t m4-7; stage buf0.B (t+2); vmcnt(4) -> buf1 (t+1) complete
            DS_A4(pA_0, 4);
            STAGE_B(0, 0, 128); STAGE_B(0, 1, 128);
            PRIO1(); MFMA_Q(4, 2, b23); MFMA_Q(4, 0, b01); PRIO0();
            asm volatile("s_waitcnt vmcnt(4)" ::: "memory");
            BAR();
            // P3: tile t+1 (buf1) m0-3; stage buf0.A (t+2)
            DS_B2(pB_1, b01, 0); DS_B2(pB_1, b23, 2);
            DS_A4(pA_1, 0);
            STAGE_A(0, 0, 128); STAGE_A(0, 1, 128);
            PRIO1(); MFMA_Q(0, 0, b01); MFMA_Q(0, 2, b23); PRIO0(); BAR();
            // P4: tile t+1 m4-7; stage buf1.B (t+3); vmcnt(4) -> buf0 (t+2) complete
            DS_A4(pA_1, 4);
            STAGE_B(1, 0, 192); STAGE_B(1, 1, 192);
            PRIO1(); MFMA_Q(4, 2, b23); MFMA_Q(4, 0, b01); PRIO0();
            asm volatile("s_waitcnt vmcnt(4)" ::: "memory");
            BAR();

            aS0h0 += 128; aS1h0 += 128; aS0h1 += 128; aS1h1 += 128;
            bS0h0 += 128; bS1h0 += 128; bS0h1 += 128; bS1h1 += 128;
        }

        // ---- peeled final pair (tiles NT-2 -> buf0, NT-1 -> buf1) ----
        DS_B2(pB_0, b01, 0); DS_B2(pB_0, b23, 2);
        DS_A4(pA_0, 0);
        STAGE_A(1, 0, 64); STAGE_A(1, 1, 64);
        PRIO1(); MFMA_Q(0, 0, b01); MFMA_Q(0, 2, b23); PRIO0(); BAR();
        DS_A4(pA_0, 4);
        PRIO1(); MFMA_Q(4, 2, b23); MFMA_Q(4, 0, b01); PRIO0();
        asm volatile("s_waitcnt vmcnt(0)" ::: "memory");
        BAR();
        DS_B2(pB_1, b01, 0); DS_B2(pB_1, b23, 2);
        DS_A4(pA_1, 0);
        PRIO1(); MFMA_Q(0, 0, b01); MFMA_Q(0, 2, b23); PRIO0(); BAR();
        DS_A4(pA_1, 4);
        PRIO1(); MFMA_Q(4, 2, b23); MFMA_Q(4, 0, b01); PRIO0();

        // all waves' LDS reads must retire before next half re-stages the buffers
        BAR();

        // ---- epilogue: ALL-INTEGER exact exponent decision + flag + finalize ----
        // S >= 0 always (sum of positive powers of two). For normal S:
        //   rlog2(S) = (E-127) + (m23 >= 0x3504F4)   [m52 = m23<<29 equivalence, exact]
        // finalize(2^em + 2^ebj): d=0 -> hi+1; d=1 (1.5 >= sqrt2) -> hi+1; d>=2 -> hi;
        //   ">1e-38" mask <=> hi >= -126 || (hi == -127 && d == 0); 2^-128 fp32 = 0x00200000.
#pragma unroll
        for (int m = 0; m < 8; ++m) {
            int grow_base = brow + wm * 128 + m * 16 + lhi * 4;
#pragma unroll
            for (int n = 0; n < 4; ++n) {
                int gcol = bcol + wn * 64 + n * 16 + l15;
                int ebj = eb[gcol];
#pragma unroll
                for (int q = 0; q < 4; ++q) {
                    float S = acc[m][n][q];
                    int grow = grow_base + q;
                    unsigned ub = __float_as_uint(S);
                    int E = (int)(ub >> 23);
                    int em; bool flag;
                    if (E == 0 || E == 255) {       // zero/denorm/inf/nan -> exact fixup
                        em = E ? 127 : -128; flag = true;
                    } else {
                        int m23 = (int)(ub & 0x7FFFFF);
                        int dd = m23 - SQRT2_M23;
                        flag = (dd < 0 ? -dd : dd) < FLAG_M23;
                        em = (E - 127) + (int)(m23 >= SQRT2_M23);
                        if (em > 127) em = 127;
                    }
                    int hi = em > ebj ? em : ebj;
                    int d  = em > ebj ? em - ebj : ebj - em;
                    int eo;
                    if (hi >= -126 || (hi == -127 && d == 0)) {
                        eo = hi + (d <= 1);
                        if (eo > 127) eo = 127;
                    } else eo = -128;
                    unsigned obits = (eo >= -126) ? ((unsigned)(eo + 127) << 23) : 0x00200000u;
                    out[(size_t)grow * N_COLS + gcol] = __uint_as_float(obits);
                    if (flag) {
                        int pos = atomicAdd(wl_count, 1);
                        if (pos < WL_CAP) wl[pos] = grow * N_COLS + gcol;
                    }
                }
            }
        }
    }
}

// ---------------- exact fixup for flagged outputs ----------------
__global__ __launch_bounds__(256) void fixup_kernel(
    const unsigned short* __restrict__ xq, const unsigned short* __restrict__ wq,
    const int* __restrict__ eb, float* __restrict__ out,
    const int* __restrict__ wl_count, const int* __restrict__ wl)
{
    const int nwaves = (gridDim.x * blockDim.x) >> 6;
    const int gw = (blockIdx.x * blockDim.x + threadIdx.x) >> 6;
    const int lane = threadIdx.x & 63;
    int count = *wl_count;
    if (count > WL_CAP) count = WL_CAP;
    for (int it = gw; it < count; it += nwaves) {
        int lin = wl[it];
        int i = lin >> 12;
        int j = lin & 4095;
        const unsigned short* xr = xq + (size_t)i * K_DIM;
        const unsigned short* wr = wq + (size_t)j * K_DIM;
        unsigned long long accu = 0;
        for (int kb = 0; kb < K_DIM / 256; ++kb) {
            int k0 = kb * 256 + lane * 4;
            ushort4 xv = *(const ushort4*)(xr + k0);
            ushort4 wv = *(const ushort4*)(wr + k0);
            int p;
            p = bf16_exp(xv.x) + bf16_exp(wv.x) + 56; if ((unsigned)p <= 62u) accu += 1ULL << p;
            p = bf16_exp(xv.y) + bf16_exp(wv.y) + 56; if ((unsigned)p <= 62u) accu += 1ULL << p;
            p = bf16_exp(xv.z) + bf16_exp(wv.z) + 56; if ((unsigned)p <= 62u) accu += 1ULL << p;
            p = bf16_exp(xv.w) + bf16_exp(wv.w) + 56; if ((unsigned)p <= 62u) accu += 1ULL << p;
        }
#pragma unroll
        for (int off = 32; off; off >>= 1) accu += __shfl_down(accu, off, 64);
        if (lane == 0) {
            double S = (double)accu * 0x1p-56;
            int em = rlog2_mask(S);
            out[lin] = finalize_out(em, eb[j]);
        }
    }
}

extern "C" void kernel_launch(void* const* d_in, const int* in_sizes, int n_in,
                              void* d_out, int out_size, void* d_ws, size_t ws_size,
                              hipStream_t stream) {
    const float* x    = (const float*)d_in[0];
    const float* w    = (const float*)d_in[1];
    const float* bias = (const float*)d_in[2];
    float* out = (float*)d_out;
    char* ws = (char*)d_ws;

    int* wl_count = (int*)ws;
    int* eb       = (int*)(ws + 256);
    unsigned short* xq = (unsigned short*)(ws + 32768);
    unsigned short* wq = (unsigned short*)(ws + 32768 + (size_t)M_ROWS * K_DIM * 2);
    int* wl = (int*)(ws + 32768 + (size_t)M_ROWS * K_DIM * 2 + (size_t)N_COLS * K_DIM * 2);

    prep_kernel<<<3072, 256, 0, stream>>>(x, w, bias, xq, wq, eb, wl_count,
                                          M_ROWS * K_DIM / 4, N_COLS * K_DIM / 4);
    gemm_kernel<<<dim3(256), 512, 0, stream>>>(xq, wq, eb, out, wl_count, wl);
    fixup_kernel<<<1024, 256, 0, stream>>>(xq, wq, eb, out, wl_count, wl);
}

// Round 21
// 270.771 us; speedup vs baseline: 1.0278x; 1.0278x over previous
//
#include <hip/hip_runtime.h>
#include <hip/hip_bf16.h>
#include <stdint.h>

typedef __attribute__((ext_vector_type(8))) short short8;
typedef __attribute__((ext_vector_type(4))) float f32x4;

#define M_ROWS 8192
#define K_DIM  4096
#define N_COLS 4096
#define NT     (K_DIM / 64)   // 64 K-tiles
#define WL_CAP (1 << 20)

// sqrt(2) in fp64: 0x3FF6A09E667F3BCD (slightly ABOVE true sqrt2).
#define SQRT2_MANT 0x6A09E667F3BCDLL
// fp32 equivalent: m23 >= 0x3504F4  <=>  (m23<<29) >= SQRT2_MANT  (exact)
#define SQRT2_M23 0x3504F4
// flag margin: ~2^-11 relative; hard MFMA accumulation error bound is 2^-12
#define FLAG_MARGIN 3110000000000LL

__device__ __forceinline__ int rlog2_mask(double a) {
    if (!(a > 1e-38)) return -128;
    long long b = __double_as_longlong(a);
    int E = (int)(b >> 52) - 1023;
    long long m = b & 0xFFFFFFFFFFFFFLL;
    int e = E + (int)(m >= SQRT2_MANT);
    return e < -128 ? -128 : (e > 127 ? 127 : e);
}

__device__ __forceinline__ double pow2d(int e) {
    return __longlong_as_double((long long)(e + 1023) << 52);
}

__device__ __forceinline__ unsigned short bf16_pow2(int e) {
    if (e >= -126) return (unsigned short)((e + 127) << 7);
    int sh = 133 + e;
    return (unsigned short)(sh >= 0 ? (1 << sh) : 0);
}

__device__ __forceinline__ int bf16_exp(unsigned short u) {
    int ex = (u >> 7) & 0xFF;
    if (ex) return ex - 127;
    int m = u & 0x7F;
    return m ? (-133 + (31 - __clz(m))) : -1000;
}

__device__ __forceinline__ float finalize_out(int em, int ebj) {
    double s = pow2d(em) + pow2d(ebj);
    return (float)pow2d(rlog2_mask(s));
}

// ---------------- fused prep: wl_count reset + bias quant + x/w quant ----------------
__device__ __forceinline__ unsigned short qbf16(float f) {
    unsigned u = __float_as_uint(f) & 0x7FFFFFFFu;  // |f| bits
    int E = (int)(u >> 23);
    if (E == 0 || E == 255) {
        return bf16_pow2(rlog2_mask(fabs((double)f)));  // denorm/zero/inf/nan slow path
    }
    int e = (E - 127) + (int)((u & 0x7FFFFFu) >= SQRT2_M23);
    e = e > 127 ? 127 : e;
    return (unsigned short)((e + 127) << 7);
}

__device__ __forceinline__ ushort4 quant4(float4 v) {
    ushort4 o;
    o.x = qbf16(v.x);
    o.y = qbf16(v.y);
    o.z = qbf16(v.z);
    o.w = qbf16(v.w);
    return o;
}

__global__ void prep_kernel(const float* __restrict__ x, const float* __restrict__ w,
                            const float* __restrict__ bias,
                            unsigned short* __restrict__ xq, unsigned short* __restrict__ wq,
                            int* __restrict__ eb, int* __restrict__ wl_count,
                            int nx4, int nw4) {
    int idx = blockIdx.x * blockDim.x + threadIdx.x;
    if (idx == 0) *wl_count = 0;
    if (idx < N_COLS) eb[idx] = rlog2_mask(fabs((double)bias[idx]));
    int stride = gridDim.x * blockDim.x;
    int total = nx4 + nw4;
    for (int i = idx; i < total; i += stride) {
        if (i < nx4) {
            float4 v = ((const float4*)x)[i];
            ((ushort4*)xq)[i] = quant4(v);
        } else {
            float4 v = ((const float4*)w)[i - nx4];
            ((ushort4*)wq)[i - nx4] = quant4(v);
        }
    }
}

// ---------------- 256x256 GEMM (16x16x32 MFMA, persistent 2-tile blocks) ----------------
__device__ __forceinline__ void g2lds16(const unsigned short* g, unsigned short* l) {
    __builtin_amdgcn_global_load_lds(
        (const __attribute__((address_space(1))) unsigned int*)g,
        (__attribute__((address_space(3))) unsigned int*)l, 16, 0, 0);
}

#define LD8(p, off) (*(const short8*)((const char*)(p) + (off)))
#define MFMA16(a, b, c) __builtin_amdgcn_mfma_f32_16x16x32_bf16((a), (b), (c), 0, 0, 0)

__global__ __launch_bounds__(512, 2) void gemm_kernel(
    const unsigned short* __restrict__ xq, const unsigned short* __restrict__ wq,
    const int* __restrict__ eb, float* __restrict__ out,
    int* __restrict__ wl_count, int* __restrict__ wl)
{
    // Per 64KB buffer (shorts): A0 [0,8192) A1 [8192,16384) B0 [16384,24576) B1 [24576,32768)
    // 16KB half-tile = [2 kk][128 rows][32 cols] bf16, 64B row pitch,
    // st_16x32 swizzle: byte ^= ((byte>>9)&1)<<5.
    __shared__ unsigned short lds[2][32768];

    const int tid = threadIdx.x;
    const int lane = tid & 63, w = tid >> 6;
    const int wm = w >> 2, wn = w & 3;
    const int l15 = lane & 15, lhi = lane >> 4;

    // Persistent 2D XCD tiling: 256 blocks (1/CU), each does 2 M-tiles.
    const int x = blockIdx.x & 7;
    const int j = blockIdx.x >> 3;          // 0..31
    const int bm0 = (x & 3) * 8 + (j & 3);  // tile 1; tile 2 = bm0 + 4
    const int bn  = (x >> 2) * 8 + (j >> 2);
    const int bcol = bn * 256;

    // staging thread->coord (pre-swizzled global, linear LDS dest)
    int p0 = tid * 16;
    int lin0 = p0 ^ (((p0 >> 9) & 1) << 5);
    int row0 = (lin0 >> 6) & 127;
    int col0 = (((lin0 >> 13) << 6) | (lin0 & 63)) >> 1;
    int p1 = 8192 + tid * 16;
    int lin1 = p1 ^ (((p1 >> 9) & 1) << 5);
    int row1 = (lin1 >> 6) & 127;
    int col1 = (((lin1 >> 13) << 6) | (lin1 & 63)) >> 1;

    // fragment read base (bytes, swizzled)
    int fsw = l15 * 64 + lhi * 16;
    fsw ^= ((l15 >> 3) & 1) << 5;

    const char* pA_0 = (const char*)&lds[0][wm * 8192] + fsw;
    const char* pA_1 = (const char*)&lds[1][wm * 8192] + fsw;
    const char* pB_0 = (const char*)&lds[0][16384 + (wn >> 1) * 8192 + (wn & 1) * 2048] + fsw;
    const char* pB_1 = (const char*)&lds[1][16384 + (wn >> 1) * 8192 + (wn & 1) * 2048] + fsw;

#define STAGE_A(b, h, OFFE) do { \
        g2lds16(((h) ? aS0h1 : aS0h0) + (OFFE), &lds[b][(h) * 8192] + wofs); \
        g2lds16(((h) ? aS1h1 : aS1h0) + (OFFE), &lds[b][(h) * 8192 + 4096] + wofs); \
    } while (0)
#define STAGE_B(b, h, OFFE) do { \
        g2lds16(((h) ? bS0h1 : bS0h0) + (OFFE), &lds[b][16384 + (h) * 8192] + wofs); \
        g2lds16(((h) ? bS1h1 : bS1h0) + (OFFE), &lds[b][16384 + (h) * 8192 + 4096] + wofs); \
    } while (0)
#define DS_A4(P, mb) do { \
        aF[0][0] = LD8(P, ((mb) + 0) * 1024); aF[0][1] = LD8(P, ((mb) + 0) * 1024 + 8192); \
        aF[1][0] = LD8(P, ((mb) + 1) * 1024); aF[1][1] = LD8(P, ((mb) + 1) * 1024 + 8192); \
        aF[2][0] = LD8(P, ((mb) + 2) * 1024); aF[2][1] = LD8(P, ((mb) + 2) * 1024 + 8192); \
        aF[3][0] = LD8(P, ((mb) + 3) * 1024); aF[3][1] = LD8(P, ((mb) + 3) * 1024 + 8192); \
    } while (0)
#define DS_B2(P, arr, cb) do { \
        arr[0][0] = LD8(P, ((cb) + 0) * 1024); arr[0][1] = LD8(P, ((cb) + 0) * 1024 + 8192); \
        arr[1][0] = LD8(P, ((cb) + 1) * 1024); arr[1][1] = LD8(P, ((cb) + 1) * 1024 + 8192); \
    } while (0)
#define MFMA_Q(mb, nb, B) do { \
        _Pragma("unroll") \
        for (int m_ = 0; m_ < 4; ++m_) \
        _Pragma("unroll") \
        for (int n_ = 0; n_ < 2; ++n_) { \
            acc[(mb) + m_][(nb) + n_] = MFMA16(aF[m_][0], B[n_][0], acc[(mb) + m_][(nb) + n_]); \
            acc[(mb) + m_][(nb) + n_] = MFMA16(aF[m_][1], B[n_][1], acc[(mb) + m_][(nb) + n_]); \
        } \
    } while (0)

#define BAR()  __builtin_amdgcn_s_barrier()
#define PRIO1() __builtin_amdgcn_s_setprio(1)
#define PRIO0() __builtin_amdgcn_s_setprio(0)

    const int wofs = w * 512;

    for (int ht = 0; ht < 2; ++ht) {
        const int bm = bm0 + ht * 4;
        const int brow = bm * 256;

        // 8 rolling global pointers (advance +128 elems / iteration = 2 K-tiles)
        const unsigned short* aS0h0 = xq + (size_t)(brow + row0) * K_DIM + col0;
        const unsigned short* aS1h0 = xq + (size_t)(brow + row1) * K_DIM + col1;
        const unsigned short* aS0h1 = aS0h0 + (size_t)128 * K_DIM;
        const unsigned short* aS1h1 = aS1h0 + (size_t)128 * K_DIM;
        const unsigned short* bS0h0 = wq + (size_t)(bcol + row0) * K_DIM + col0;
        const unsigned short* bS1h0 = wq + (size_t)(bcol + row1) * K_DIM + col1;
        const unsigned short* bS0h1 = bS0h0 + (size_t)128 * K_DIM;
        const unsigned short* bS1h1 = bS1h0 + (size_t)128 * K_DIM;

        f32x4 acc[8][4];
#pragma unroll
        for (int m = 0; m < 8; ++m)
#pragma unroll
            for (int n = 0; n < 4; ++n) acc[m][n] = (f32x4){0.f, 0.f, 0.f, 0.f};

        short8 aF[4][2], b01[2][2], b23[2][2];

        // ---- prologue: tile0 -> buf0 (A0,A1,B0,B1), tile1 -> buf1 (B0,B1) ----
        STAGE_A(0, 0, 0);
        STAGE_A(0, 1, 0);
        STAGE_B(0, 0, 0);
        STAGE_B(0, 1, 0);
        STAGE_B(1, 0, 64);
        STAGE_B(1, 1, 64);
        asm volatile("s_waitcnt vmcnt(4)" ::: "memory");
        BAR();

        // ---- main loop: 2 K-tiles (2tt -> buf0, 2tt+1 -> buf1), 4 mega-phases ----
        for (int tt = 0; tt < NT / 2 - 1; ++tt) {
            // P1: tile t (buf0) m0-3 x all n; stage buf1.A (t+1)
            DS_B2(pB_0, b01, 0); DS_B2(pB_0, b23, 2);
            DS_A4(pA_0, 0);
            STAGE_A(1, 0, 64); STAGE_A(1, 1, 64);
            PRIO1(); MFMA_Q(0, 0, b01); MFMA_Q(0, 2, b23); PRIO0(); BAR();
            // P2: tile t m4-7; stage buf0.B (t+2); vmcnt(4) -> buf1 (t+1) complete
            DS_A4(pA_0, 4);
            STAGE_B(0, 0, 128); STAGE_B(0, 1, 128);
            PRIO1(); MFMA_Q(4, 2, b23); MFMA_Q(4, 0, b01); PRIO0();
            asm volatile("s_waitcnt vmcnt(4)" ::: "memory");
            BAR();
            // P3: tile t+1 (buf1) m0-3; stage buf0.A (t+2)
            DS_B2(pB_1, b01, 0); DS_B2(pB_1, b23, 2);
            DS_A4(pA_1, 0);
            STAGE_A(0, 0, 128); STAGE_A(0, 1, 128);
            PRIO1(); MFMA_Q(0, 0, b01); MFMA_Q(0, 2, b23); PRIO0(); BAR();
            // P4: tile t+1 m4-7; stage buf1.B (t+3); vmcnt(4) -> buf0 (t+2) complete
            DS_A4(pA_1, 4);
            STAGE_B(1, 0, 192); STAGE_B(1, 1, 192);
            PRIO1(); MFMA_Q(4, 2, b23); MFMA_Q(4, 0, b01); PRIO0();
            asm volatile("s_waitcnt vmcnt(4)" ::: "memory");
            BAR();

            aS0h0 += 128; aS1h0 += 128; aS0h1 += 128; aS1h1 += 128;
            bS0h0 += 128; bS1h0 += 128; bS0h1 += 128; bS1h1 += 128;
        }

        // ---- peeled final pair (tiles NT-2 -> buf0, NT-1 -> buf1) ----
        DS_B2(pB_0, b01, 0); DS_B2(pB_0, b23, 2);
        DS_A4(pA_0, 0);
        STAGE_A(1, 0, 64); STAGE_A(1, 1, 64);
        PRIO1(); MFMA_Q(0, 0, b01); MFMA_Q(0, 2, b23); PRIO0(); BAR();
        DS_A4(pA_0, 4);
        PRIO1(); MFMA_Q(4, 2, b23); MFMA_Q(4, 0, b01); PRIO0();
        asm volatile("s_waitcnt vmcnt(0)" ::: "memory");
        BAR();
        DS_B2(pB_1, b01, 0); DS_B2(pB_1, b23, 2);
        DS_A4(pA_1, 0);
        PRIO1(); MFMA_Q(0, 0, b01); MFMA_Q(0, 2, b23); PRIO0(); BAR();
        DS_A4(pA_1, 4);
        PRIO1(); MFMA_Q(4, 2, b23); MFMA_Q(4, 0, b01); PRIO0();

        // all waves' LDS reads must retire before next half re-stages the buffers
        BAR();

        // ---- epilogue: exponent decision + flag + finalize ----
#pragma unroll
        for (int m = 0; m < 8; ++m) {
            int grow_base = brow + wm * 128 + m * 16 + lhi * 4;
#pragma unroll
            for (int n = 0; n < 4; ++n) {
                int gcol = bcol + wn * 64 + n * 16 + l15;
                int ebj = eb[gcol];
#pragma unroll
                for (int q = 0; q < 4; ++q) {
                    float S = acc[m][n][q];
                    int grow = grow_base + q;
                    double v = (double)S;
                    int em; bool flag;
                    if (v > 1e-38) {
                        long long bb = __double_as_longlong(v);
                        long long mm = bb & 0xFFFFFFFFFFFFFLL;
                        long long d = mm - SQRT2_MANT;
                        flag = (d < 0 ? -d : d) < FLAG_MARGIN;
                        int e = ((int)(bb >> 52) - 1023) + (int)(mm >= SQRT2_MANT);
                        em = e < -128 ? -128 : (e > 127 ? 127 : e);
                    } else { em = -128; flag = true; }
                    out[(size_t)grow * N_COLS + gcol] = finalize_out(em, ebj);
                    if (flag) {
                        int pos = atomicAdd(wl_count, 1);
                        if (pos < WL_CAP) wl[pos] = grow * N_COLS + gcol;
                    }
                }
            }
        }
    }
}

// ---------------- exact fixup for flagged outputs ----------------
__global__ __launch_bounds__(256) void fixup_kernel(
    const unsigned short* __restrict__ xq, const unsigned short* __restrict__ wq,
    const int* __restrict__ eb, float* __restrict__ out,
    const int* __restrict__ wl_count, const int* __restrict__ wl)
{
    const int nwaves = (gridDim.x * blockDim.x) >> 6;
    const int gw = (blockIdx.x * blockDim.x + threadIdx.x) >> 6;
    const int lane = threadIdx.x & 63;
    int count = *wl_count;
    if (count > WL_CAP) count = WL_CAP;
    for (int it = gw; it < count; it += nwaves) {
        int lin = wl[it];
        int i = lin >> 12;
        int j = lin & 4095;
        const unsigned short* xr = xq + (size_t)i * K_DIM;
        const unsigned short* wr = wq + (size_t)j * K_DIM;
        unsigned long long accu = 0;
        for (int kb = 0; kb < K_DIM / 256; ++kb) {
            int k0 = kb * 256 + lane * 4;
            ushort4 xv = *(const ushort4*)(xr + k0);
            ushort4 wv = *(const ushort4*)(wr + k0);
            int p;
            p = bf16_exp(xv.x) + bf16_exp(wv.x) + 56; if ((unsigned)p <= 62u) accu += 1ULL << p;
            p = bf16_exp(xv.y) + bf16_exp(wv.y) + 56; if ((unsigned)p <= 62u) accu += 1ULL << p;
            p = bf16_exp(xv.z) + bf16_exp(wv.z) + 56; if ((unsigned)p <= 62u) accu += 1ULL << p;
            p = bf16_exp(xv.w) + bf16_exp(wv.w) + 56; if ((unsigned)p <= 62u) accu += 1ULL << p;
        }
#pragma unroll
        for (int off = 32; off; off >>= 1) accu += __shfl_down(accu, off, 64);
        if (lane == 0) {
            double S = (double)accu * 0x1p-56;
            int em = rlog2_mask(S);
            out[lin] = finalize_out(em, eb[j]);
        }
    }
}

extern "C" void kernel_launch(void* const* d_in, const int* in_sizes, int n_in,
                              void* d_out, int out_size, void* d_ws, size_t ws_size,
                              hipStream_t stream) {
    const float* x    = (const float*)d_in[0];
    const float* w    = (const float*)d_in[1];
    const float* bias = (const float*)d_in[2];
    float* out = (float*)d_out;
    char* ws = (char*)d_ws;

    int* wl_count = (int*)ws;
    int* eb       = (int*)(ws + 256);
    unsigned short* xq = (unsigned short*)(ws + 32768);
    unsigned short* wq = (unsigned short*)(ws + 32768 + (size_t)M_ROWS * K_DIM * 2);
    int* wl = (int*)(ws + 32768 + (size_t)M_ROWS * K_DIM * 2 + (size_t)N_COLS * K_DIM * 2);

    prep_kernel<<<3072, 256, 0, stream>>>(x, w, bias, xq, wq, eb, wl_count,
                                          M_ROWS * K_DIM / 4, N_COLS * K_DIM / 4);
    gemm_kernel<<<dim3(256), 512, 0, stream>>>(xq, wq, eb, out, wl_count, wl);
    fixup_kernel<<<1024, 256, 0, stream>>>(xq, wq, eb, out, wl_count, wl);
}